// Round 6
// baseline (181.665 us; speedup 1.0000x reference)
//
#include <hip/hip_runtime.h>
#include <math.h>

typedef short v4s __attribute__((ext_vector_type(4)));
typedef short v8s __attribute__((ext_vector_type(8)));
typedef float v4f __attribute__((ext_vector_type(4)));

#define L2E 1.4426950408889634f
#define INV_SCALE 0.08838834764831845f       // 1/sqrt(128)
#define SCL2 (INV_SCALE * L2E)               // folded scale for exp2

static __device__ __forceinline__ short f2bf(float x) {
    union { float f; unsigned u; } c; c.f = x;
    unsigned u = c.u;
    unsigned r = (u + 0x7fffu + ((u >> 16) & 1u)) >> 16;  // RNE
    return (short)r;
}

static __device__ __forceinline__ v4f mfma16(v4s a, v4s b, v4f c) {
#if __has_builtin(__builtin_amdgcn_mfma_f32_16x16x16_bf16)
    return __builtin_amdgcn_mfma_f32_16x16x16_bf16(a, b, c, 0, 0, 0);
#else
    return __builtin_amdgcn_mfma_f32_16x16x16bf16_1k(a, b, c, 0, 0, 0);
#endif
}

typedef __attribute__((address_space(3))) void lds_vt;
typedef __attribute__((address_space(1))) const void gl_vt;
static __device__ __forceinline__ void gload_lds16(const void* g, void* l) {
    __builtin_amdgcn_global_load_lds((gl_vt*)g, (lds_vt*)l, 16, 0, 0);
}

// ---- P0 fused: 512 blocks. isel=0: ctx gemm->Qa. isel=1: qry gemm->Ka
// PLUS fused qry transpose->VaT (plain [d][kv] bf16) + maskadd.
// qry is read ONCE (the gemm's X loads feed the transpose via LDS Tt).
// VaT writes are v8s (16B/lane, 8 rows x 128B per wave instr).
__global__ __launch_bounds__(256) void k_pre(const float* __restrict__ ctx,
                                             const float* __restrict__ qry,
                                             const float* __restrict__ Win,
                                             const float* __restrict__ Wmem,
                                             const int* __restrict__ qmask,
                                             short* __restrict__ Qa,
                                             short* __restrict__ Ka,
                                             short* __restrict__ VaT,
                                             float* __restrict__ maskadd) {
    __shared__ __align__(16) short WtS[128 * 132];      // 33792 B
    __shared__ __align__(16) short Tt[256 * 72];        // 36864 B ([k][row64+pad])
    int x = blockIdx.x;
    int tid = threadIdx.x;
    int msel = x & 255, isel = x >> 8;
    const float* X = isel ? qry : ctx;
    const float* W = isel ? Wmem : Win;
    short* Y = isel ? Ka : Qa;

    int w = tid >> 6, lane = tid & 63;
    int ln = lane & 15, qd = lane >> 4;
    int m0 = msel * 64 + w * 16;
    v4f zero = {0.f, 0.f, 0.f, 0.f};
    v4f o[8];
#pragma unroll
    for (int i = 0; i < 8; ++i) o[i] = zero;

#pragma unroll 1
    for (int kh = 0; kh < 2; ++kh) {
        if (kh) __syncthreads();                        // protect WtS reuse
        // stage W k-half: 128 f x 128 k
#pragma unroll 8
        for (int i = 0; i < 64; ++i) {
            int id = i * 256 + tid;
            int k = id >> 7, fp = id & 127;
            WtS[fp * 132 + k] = f2bf(W[(kh * 128 + k) * 128 + fp]);
        }
        __syncthreads();
#pragma unroll
        for (int kk = 0; kk < 4; ++kk) {
            const float* xp = X + (size_t)(m0 + ln) * 256 + kh * 128 + kk * 32 + qd * 8;
            float4 x0 = *(const float4*)xp;
            float4 x1 = *(const float4*)(xp + 4);
            v8s a;
            a[0] = f2bf(x0.x); a[1] = f2bf(x0.y); a[2] = f2bf(x0.z); a[3] = f2bf(x0.w);
            a[4] = f2bf(x1.x); a[5] = f2bf(x1.y); a[6] = f2bf(x1.z); a[7] = f2bf(x1.w);
            if (isel) {                                  // fused transpose staging
#pragma unroll
                for (int si = 0; si < 8; ++si)
                    Tt[(kh * 128 + kk * 32 + qd * 8 + si) * 72 + (w * 16 + ln)] = a[si];
            }
#pragma unroll
            for (int nt = 0; nt < 8; ++nt) {
                v8s bfr = *(const v8s*)(WtS + (nt * 16 + ln) * 132 + kk * 32 + qd * 8);
                o[nt] = __builtin_amdgcn_mfma_f32_16x16x32_bf16(a, bfr, o[nt], 0, 0, 0);
            }
        }
    }
#pragma unroll
    for (int nt = 0; nt < 8; ++nt) {
#pragma unroll
        for (int r = 0; r < 4; ++r) {
            float v = o[nt][r];
            v = v > 0.f ? v : 0.01f * (__expf(v) - 1.f);
            Y[(size_t)(m0 + qd * 4 + r) * 128 + nt * 16 + ln] = f2bf(v);
        }
    }

    if (isel) {
        __syncthreads();                                 // Tt complete
        int b2 = msel >> 5, q0 = (msel & 31) * 64;
        int dr = tid >> 3, j = tid & 7;
#pragma unroll
        for (int i = 0; i < 8; ++i) {
            int d = dr + i * 32;
            v8s vv = *(const v8s*)(Tt + d * 72 + j * 8);
            *(v8s*)(VaT + ((size_t)(b2 * 256 + d)) * 2048 + q0 + j * 8) = vv;
        }
        if (tid < 64) {
            int qq = b2 * 2048 + q0 + tid;
            maskadd[qq] = (qmask[qq] > 0) ? 0.f : -__builtin_inff();
        }
    }
}

// ------------- flash attention: register-P, 1 barrier per 64-kv tile ------
// 256 blocks x 512 thr (64 c each; b=blk&7 for XCD L2 locality). Wave w:
// g=w>>2 (kv half), cw=(w>>1)&1 (32 c), dv=w&1 (128 d). Per 16-kv sub-step:
// QK via mfma(K,Q) leaves S' at lane layout [kv=qd*4+r][c=ln], which IS the
// A-fragment of v_mfma_f32_16x16x16_bf16 -> softmax+PV are lane-local, NO
// P through LDS, NO lgkmcnt/barrier in the sub-steps. V tile [256d][64kv]
// staged per group via async global_load_lds (16B-granule XOR swizzle via
// pre-swizzled SOURCE, linear LDS dest - m173 pattern), double-buffered:
// exactly ONE vmcnt(0)+s_barrier per 64-kv tile (stage had a full tile to
// land). Epilogue: g1 dumps O to LDS, g0 merges+normalizes+writes out.
__global__ __launch_bounds__(512, 2) void k_attn(const short* __restrict__ Qa,
                                                 const short* __restrict__ Ka,
                                                 const short* __restrict__ VaT,
                                                 const float* __restrict__ maskadd,
                                                 float* __restrict__ out) {
    __shared__ __align__(16) short VaS[2][2][256 * 64];  // 128 KB [grp][buf][d][kv]
    __shared__ float lS[256];                            // [8 waves][32 c]

    int blk = blockIdx.x;
    int b = blk & 7;
    int c0 = (blk >> 3) * 64;

    int tid = threadIdx.x;
    int w = tid >> 6, lane = tid & 63, ln = lane & 15, qd = lane >> 4;
    int g = w >> 2, wl = w & 3, cw = (w >> 1) & 1, dv = w & 1;
    int kv0 = g * 1024;

    const short* kbase = Ka + ((size_t)(b * 2048 + kv0 + ln)) * 128 + qd * 8;
    const short* vbase = VaT + (size_t)b * 256 * 2048;
    const float* mbase = maskadd + b * 2048 + kv0 + qd * 4;

    // Q fragments: 2 c-tiles of 16 (B-operand layout), resident
    v8s qf[2][4];
#pragma unroll
    for (int ct = 0; ct < 2; ++ct) {
        const short* qp = Qa + ((size_t)(b * 2048 + c0 + cw * 32 + ct * 16 + ln)) * 128 + qd * 8;
#pragma unroll
        for (int kk = 0; kk < 4; ++kk) qf[ct][kk] = *(const v8s*)(qp + kk * 32);
    }

    v4f zero = {0.f, 0.f, 0.f, 0.f};
    v4f o[2][8];                            // [ct][dt] -> out[c][dv*128+dt*16+ln]
#pragma unroll
    for (int i = 0; i < 2; ++i)
#pragma unroll
        for (int j = 0; j < 8; ++j) o[i][j] = zero;
    float lacc[2] = {0.f, 0.f};

    // group-cooperative stage of V tile [256 d][64 kv] for window q0s.
    // LDS unit U (16B) at row d=U>>3, slot u=U&7 holds global granule
    // u^(d&7)  -> conflict-free b64 reads in PV.
    auto stageV = [&](int q0s, int buf) {
        short* ldsb = &VaS[g][buf][0];
#pragma unroll
        for (int j = 0; j < 8; ++j) {
            int U = j * 256 + wl * 64 + lane;
            int d = U >> 3, u = U & 7;
            gload_lds16(vbase + (size_t)d * 2048 + q0s + ((u ^ (d & 7)) << 3),
                        ldsb + (size_t)(j * 256 + wl * 64) * 8);
        }
    };

    stageV(kv0, 0);
    asm volatile("s_waitcnt vmcnt(0)" ::: "memory");
    __syncthreads();

#pragma unroll 1
    for (int t = 0; t < 16; ++t) {
        stageV(kv0 + ((t + 1) & 15) * 64, (t & 1) ^ 1);  // full-tile window
        const short* vs = &VaS[g][t & 1][0];
        const short* kt = kbase + (size_t)t * 8192;
        const float* mt = mbase + t * 64;
#pragma unroll
        for (int s = 0; s < 4; ++s) {
            v8s kf[4];
#pragma unroll
            for (int kk = 0; kk < 4; ++kk)
                kf[kk] = *(const v8s*)(kt + s * 2048 + kk * 32);
            float4 mk = *(const float4*)(mt + s * 16);
            v4s pw[2];
#pragma unroll
            for (int ct = 0; ct < 2; ++ct) {
                v4f sa = zero;
#pragma unroll
                for (int kk = 0; kk < 4; ++kk)
                    sa = __builtin_amdgcn_mfma_f32_16x16x32_bf16(kf[kk], qf[ct][kk], sa, 0, 0, 0);
                int cg = c0 + cw * 32 + ct * 16 + ln;
                int kvg = kv0 + t * 64 + s * 16 + qd * 4;
#pragma unroll
                for (int r = 0; r < 4; ++r) {
                    float v = sa[r] * SCL2 + (&mk.x)[r];
                    if (kvg + r == cg) v = -__builtin_inff();
                    float p = exp2f(v);
                    lacc[ct] += p;
                    pw[ct][r] = f2bf(p);
                }
            }
            // PV: P is already the 16x16x16 A-fragment; V b64 from LDS
#pragma unroll
            for (int dt = 0; dt < 8; ++dt) {
                int d = dv * 128 + dt * 16 + ln;
                v4s vf = *(const v4s*)(vs + d * 64 +
                          (((s * 2 + (qd >> 1)) ^ (d & 7)) << 3) + ((qd & 1) << 2));
                o[0][dt] = mfma16(pw[0], vf, o[0][dt]);
                o[1][dt] = mfma16(pw[1], vf, o[1][dt]);
            }
        }
        asm volatile("s_waitcnt vmcnt(0)" ::: "memory");  // stage(t+1) landed
        __builtin_amdgcn_s_barrier();                     // buffer swap
    }

    // ---- epilogue: l reduce, cross-group O merge via LDS, direct out ----
    float lv0 = lacc[0], lv1 = lacc[1];
    lv0 += __shfl_xor(lv0, 16); lv0 += __shfl_xor(lv0, 32);
    lv1 += __shfl_xor(lv1, 16); lv1 += __shfl_xor(lv1, 32);
    if (lane < 16) { lS[w * 32 + ln] = lv0; lS[w * 32 + 16 + ln] = lv1; }
    __syncthreads();

    float* OS = (float*)&VaS[0][0][0];       // [64 c][260 d-pad] f32, 66.6 KB
    if (g == 1) {
#pragma unroll
        for (int ct = 0; ct < 2; ++ct) {
            int cl = cw * 32 + ct * 16 + qd * 4;
#pragma unroll
            for (int r = 0; r < 4; ++r)
#pragma unroll
                for (int dt = 0; dt < 8; ++dt)
                    OS[(cl + r) * 260 + dv * 128 + dt * 16 + ln] = o[ct][dt][r];
        }
    }
    __syncthreads();
    if (g == 0) {
#pragma unroll
        for (int ct = 0; ct < 2; ++ct) {
            int cl = cw * 32 + ct * 16 + qd * 4;
#pragma unroll
            for (int r = 0; r < 4; ++r) {
                float ltot = lS[w * 32 + ct * 16 + qd * 4 + r]
                           + lS[(w + 4) * 32 + ct * 16 + qd * 4 + r];
                float inv = 1.f / ltot;
                size_t rowg = (size_t)(b * 2048 + c0 + cl + r);
#pragma unroll
                for (int dt = 0; dt < 8; ++dt) {
                    int col = dv * 128 + dt * 16 + ln;
                    out[rowg * 256 + col] = (o[ct][dt][r] + OS[(cl + r) * 260 + col]) * inv;
                }
            }
        }
    }
}

extern "C" void kernel_launch(void* const* d_in, const int* in_sizes, int n_in,
                              void* d_out, int out_size, void* d_ws, size_t ws_size,
                              hipStream_t stream) {
    const float* ctx  = (const float*)d_in[0];
    const float* qry  = (const float*)d_in[1];
    const float* win  = (const float*)d_in[2];
    const float* wmem = (const float*)d_in[3];
    const int* qmask  = (const int*)d_in[4];
    float* out = (float*)d_out;

    char* ws = (char*)d_ws;
    short* Qa      = (short*)(ws);                          // 4 MB
    short* Ka      = (short*)(ws + (4u << 20));             // 4 MB
    short* VaT     = (short*)(ws + (8u << 20));             // 8 MB (plain [d][kv])
    float* maskadd = (float*)(ws + (16u << 20));            // 64 KB

    k_pre<<<dim3(512), 256, 0, stream>>>(ctx, qry, win, wmem, qmask,
                                         Qa, Ka, VaT, maskadd);
    k_attn<<<dim3(256), 512, 0, stream>>>(Qa, Ka, VaT, maskadd, out);
}